// Round 1
// 578.286 us; speedup vs baseline: 1.0500x; 1.0500x over previous
//
#include <hip/hip_runtime.h>

typedef unsigned short u16t;
typedef __bf16 bf16x8 __attribute__((ext_vector_type(8)));
typedef float f32x4 __attribute__((ext_vector_type(4)));
typedef unsigned short ushort4_t __attribute__((ext_vector_type(4)));
typedef unsigned short ushort8_t __attribute__((ext_vector_type(8)));

#define B_    4
#define S_    2048
#define D_    2048
#define H_    16
#define KVH_  4
#define HD_   128
#define KDIM  2048
#define SCALE_ 0.08838834764831845f

__device__ __forceinline__ u16t f2bf(float f){
    unsigned u; __builtin_memcpy(&u, &f, 4);
    u += 0x7fffu + ((u >> 16) & 1u);
    return (u16t)(u >> 16);
}
__device__ __forceinline__ void glds16(const u16t* g, u16t* l){
    __builtin_amdgcn_global_load_lds((const __attribute__((address_space(1))) void*)g,
                                     (__attribute__((address_space(3))) void*)l, 16, 0, 0);
}
// Workgroup barrier WITHOUT the vmcnt(0) drain __syncthreads() would emit.
// LDS visibility only: in-flight global prefetch loads (private VGPR dests)
// stay outstanding across the barrier (T4 counted-vmcnt lesson).
__device__ __forceinline__ void wg_barrier_lgkm(){
    __builtin_amdgcn_sched_barrier(0);
    asm volatile("s_waitcnt lgkmcnt(0)" ::: "memory");
    __builtin_amdgcn_s_barrier();
    __builtin_amdgcn_sched_barrier(0);
}

// ---------------- fp32 -> bf16 convert (x) ----------------
__global__ void f32_to_bf16(const float* __restrict__ in, u16t* __restrict__ out)
{
    int i = (blockIdx.x * 256 + threadIdx.x) * 4;
    float4 v = *(const float4*)(in + i);
    ushort4_t p;
    p[0] = f2bf(v.x); p[1] = f2bf(v.y); p[2] = f2bf(v.z); p[3] = f2bf(v.w);
    *(ushort4_t*)(out + i) = p;
}

// ---------- weight transpose+convert: W(K,N) fp32 -> Wt(N,K) bf16 ----------
__global__ void transpose_f32_bf16(const float* __restrict__ W, u16t* __restrict__ Wt,
                                   int Ncols, int Krows)
{
    __shared__ u16t tile[32][33];
    int tx = threadIdx.x, ty = threadIdx.y;
    int n = blockIdx.x * 32 + tx, k = blockIdx.y * 32 + ty;
    tile[ty][tx] = f2bf(W[(size_t)k * Ncols + n]);
    __syncthreads();
    int nn = blockIdx.x * 32 + ty, kk = blockIdx.y * 32 + tx;
    Wt[(size_t)nn * Krows + kk] = tile[tx][ty];
}

// ============ shared GEMM main loop (128x128 tile, BK=32, m97-style) ============
#define GEMM_PROLOGUE_AND_KLOOP                                                   \
    __shared__ u16t As[128 * 32];                                                 \
    __shared__ u16t Bs[128 * 32];                                                 \
    const int tid  = threadIdx.x;                                                 \
    const int lane = tid & 63, w = tid >> 6;                                      \
    const int wr = (w >> 1) * 64, wc = (w & 1) * 64;                              \
    const int lr = lane & 15, quad = lane >> 4;                                   \
    const int m0 = blockIdx.y * 128, n0 = blockIdx.x * 128;                       \
    f32x4 acc[4][4];                                                              \
    _Pragma("unroll")                                                             \
    for (int r = 0; r < 4; r++)                                                   \
        _Pragma("unroll")                                                         \
        for (int c = 0; c < 4; c++) acc[r][c] = (f32x4){0.f, 0.f, 0.f, 0.f};      \
    for (int k0 = 0; k0 < KDIM; k0 += 32) {                                       \
        __syncthreads();                                                          \
        _Pragma("unroll")                                                         \
        for (int cc = 0; cc < 2; cc++) {                                          \
            int slot = tid + cc * 256;                                            \
            int row = slot >> 2, ko = (slot & 3) * 8;                             \
            glds16(A  + (size_t)(m0 + row) * KDIM + k0 + ko, As + slot * 8);      \
            glds16(Bt + (size_t)(n0 + row) * KDIM + k0 + ko, Bs + slot * 8);      \
        }                                                                         \
        __syncthreads();                                                          \
        bf16x8 a[4], b[4];                                                        \
        _Pragma("unroll")                                                         \
        for (int r = 0; r < 4; r++)                                               \
            a[r] = *(const bf16x8*)(As + (wr + r * 16 + lr) * 32 + quad * 8);     \
        _Pragma("unroll")                                                         \
        for (int c = 0; c < 4; c++)                                               \
            b[c] = *(const bf16x8*)(Bs + (wc + c * 16 + lr) * 32 + quad * 8);     \
        _Pragma("unroll")                                                         \
        for (int r = 0; r < 4; r++)                                               \
            _Pragma("unroll")                                                     \
            for (int c = 0; c < 4; c++)                                           \
                acc[r][c] = __builtin_amdgcn_mfma_f32_16x16x32_bf16(a[r], b[c], acc[r][c], 0, 0, 0); \
    }

// ---------------- O-projection GEMM: fp32 store to d_out ----------------
__global__ void gemm_o(const u16t* __restrict__ A, const u16t* __restrict__ Bt,
                       const float* __restrict__ bias, float* __restrict__ out)
{
    GEMM_PROLOGUE_AND_KLOOP
#pragma unroll
    for (int r = 0; r < 4; r++) {
#pragma unroll
        for (int c = 0; c < 4; c++) {
            int n = n0 + wc + c * 16 + lr;
            float bval = bias[n];
#pragma unroll
            for (int g = 0; g < 4; g++) {
                int m = m0 + wr + r * 16 + quad * 4 + g;
                out[(size_t)m * D_ + n] = acc[r][c][g] + bval;
            }
        }
    }
}

// ---------------- fused QKV GEMM over N=3072 (Bt = [Wqt;Wkt;Wvt]) ------------
__global__ void gemm_qkv(const u16t* __restrict__ A, const u16t* __restrict__ Bt,
                         const float* __restrict__ bq, const float* __restrict__ bk,
                         const float* __restrict__ bv,
                         u16t* __restrict__ q_t, u16t* __restrict__ k_t,
                         u16t* __restrict__ v_t,
                         const float* __restrict__ fc, const float* __restrict__ fs)
{
    GEMM_PROLOGUE_AND_KLOOP
    const int region = (blockIdx.x < 16) ? 0 : ((blockIdx.x < 20) ? 1 : 2);
#pragma unroll
    for (int r = 0; r < 4; r++) {
#pragma unroll
        for (int c = 0; c < 4; c++) {
            int n = n0 + wc + c * 16 + lr;
            if (region == 0) {          // Q + RoPE
                float bval = bq[n];
                int hh = n >> 7, d = n & 127, i2 = d >> 1;
#pragma unroll
                for (int g = 0; g < 4; g++) {
                    int m = m0 + wr + r * 16 + quad * 4 + g;
                    int bb = m >> 11, s = m & (S_ - 1);
                    float v = acc[r][c][g] + bval;
                    float p = __shfl_xor(v, 1);
                    float cf = fc[s * 64 + i2], sf = fs[s * 64 + i2];
                    float o = (d & 1) ? (p * sf + v * cf) : (v * cf - p * sf);
                    q_t[(((size_t)bb * H_ + hh) * S_ + s) * HD_ + d] = f2bf(o);
                }
            } else if (region == 1) {   // K + RoPE
                int nk = n - 2048;
                float bval = bk[nk];
                int hh = nk >> 7, d = nk & 127, i2 = d >> 1;
#pragma unroll
                for (int g = 0; g < 4; g++) {
                    int m = m0 + wr + r * 16 + quad * 4 + g;
                    int bb = m >> 11, s = m & (S_ - 1);
                    float v = acc[r][c][g] + bval;
                    float p = __shfl_xor(v, 1);
                    float cf = fc[s * 64 + i2], sf = fs[s * 64 + i2];
                    float o = (d & 1) ? (p * sf + v * cf) : (v * cf - p * sf);
                    k_t[(((size_t)bb * KVH_ + hh) * S_ + s) * HD_ + d] = f2bf(o);
                }
            } else {                    // V transposed
                int nv = n - 2560;
                float bval = bv[nv];
                int kv = nv >> 7, d = nv & 127;
                int mb = m0 + wr + r * 16 + quad * 4;
                int bb = mb >> 11, s = mb & (S_ - 1);
                ushort4_t pk;
#pragma unroll
                for (int g = 0; g < 4; g++) pk[g] = f2bf(acc[r][c][g] + bval);
                *(ushort4_t*)(v_t + (((size_t)bb * KVH_ + kv) * HD_ + d) * S_ + s) = pk;
            }
        }
    }
}

// ---------------- flash attention, causal, GQA (bf16 in/out) ----------------
// 8 waves / 512 threads, 128 q-rows per block. Double-buffered K/V in LDS,
// ONE raw s_barrier per tile with lgkmcnt(0) ONLY (no vmcnt drain): the
// 2-tile-deep global prefetch stays in flight across barriers. Ps rows are
// wave-private -> no barrier for the P round-trip. setprio(1) around MFMA.
#define KSTRIDE 136
#define VSTRIDE 40
__global__ __launch_bounds__(512) void
attn_kernel(const u16t* __restrict__ qt, const u16t* __restrict__ kt,
            const u16t* __restrict__ vt, u16t* __restrict__ att)
{
    __shared__ u16t Ks[2][32 * KSTRIDE];    // 17 KB
    __shared__ u16t Vs[2][128 * VSTRIDE];   // 20.5 KB (V^T: rows d, cols t)
    __shared__ u16t Ps[128 * VSTRIDE];      // 10.25 KB  (total 48.1 KB -> 3 blk/CU)
    const int tid  = threadIdx.x;
    const int lane = tid & 63, w = tid >> 6;          // w 0..7
    const int lr = lane & 15, quad = lane >> 4;
    const int bh = blockIdx.y, b = bh >> 4, h = bh & 15, kv = h >> 2;
    const int q0 = ((int)gridDim.x - 1 - (int)blockIdx.x) * 128;  // heavy blocks first

    const u16t* qb = qt + (((size_t)b * H_ + h) * S_ + q0) * HD_;
    const u16t* kb = kt + ((size_t)b * KVH_ + kv) * S_ * HD_;
    const u16t* vb = vt + ((size_t)b * KVH_ + kv) * HD_ * S_;

    // Q fragments: wave-private rows, straight from global
    bf16x8 qa[4];
#pragma unroll
    for (int ks = 0; ks < 4; ks++)
        qa[ks] = *(const bf16x8*)(qb + (w * 16 + lr) * HD_ + ks * 32 + quad * 8);

    f32x4 o[8];
#pragma unroll
    for (int i = 0; i < 8; i++) o[i] = (f32x4){0.f, 0.f, 0.f, 0.f};
    float lpart[4] = {0.f, 0.f, 0.f, 0.f};

    // staging decomposition: 512 threads, 1 granule (8 u16) per tensor each
    const int krow = tid >> 4, kgi = tid & 15;   // K tile: 32 rows x 128 d
    const int vrow = tid >> 2, vgi = tid & 3;    // V^T tile: 128 rows x 32 t

    const int ntile = q0 / 32 + 4;   // multiple of 4 -> even
    ushort8_t kr[2], vr[2];
#pragma unroll
    for (int p = 0; p < 2; p++) {
        kr[p] = *(const ushort8_t*)(kb + (size_t)(p * 32 + krow) * HD_ + kgi * 8);
        vr[p] = *(const ushort8_t*)(vb + (size_t)vrow * S_ + p * 32 + vgi * 8);
    }

    for (int it = 0; it < ntile; it += 2) {
#pragma unroll
        for (int p = 0; p < 2; p++) {
            const int t0 = (it + p) * 32;
            // stage prefetched regs -> LDS buffer p (compiler inserts counted vmcnt)
            *(ushort8_t*)(&Ks[p][krow * KSTRIDE + kgi * 8]) = kr[p];
            *(ushort8_t*)(&Vs[p][vrow * VSTRIDE + vgi * 8]) = vr[p];
            // prefetch tile it+p+2 (clamped; tail loads tile 0 harmlessly)
            const int tn0 = (it + p + 2 < ntile) ? (it + p + 2) * 32 : 0;
            kr[p] = *(const ushort8_t*)(kb + (size_t)(tn0 + krow) * HD_ + kgi * 8);
            vr[p] = *(const ushort8_t*)(vb + (size_t)vrow * S_ + tn0 + vgi * 8);
            wg_barrier_lgkm();   // LDS visible; prefetch loads stay in flight

            f32x4 sc[2];
            sc[0] = (f32x4){0.f, 0.f, 0.f, 0.f};
            sc[1] = (f32x4){0.f, 0.f, 0.f, 0.f};
            __builtin_amdgcn_s_setprio(1);
#pragma unroll
            for (int tn = 0; tn < 2; tn++)
#pragma unroll
                for (int ks = 0; ks < 4; ks++) {
                    bf16x8 kf = *(const bf16x8*)(&Ks[p][(tn * 16 + lr) * KSTRIDE + ks * 32 + quad * 8]);
                    sc[tn] = __builtin_amdgcn_mfma_f32_16x16x32_bf16(qa[ks], kf, sc[tn], 0, 0, 0);
                }
            __builtin_amdgcn_s_setprio(0);

            if (t0 + 31 <= q0 + w * 16) {
#pragma unroll
                for (int g = 0; g < 4; g++)
#pragma unroll
                    for (int tn = 0; tn < 2; tn++)
                        sc[tn][g] = __expf(sc[tn][g] * SCALE_);
            } else {
#pragma unroll
                for (int g = 0; g < 4; g++) {
                    int srow = q0 + w * 16 + quad * 4 + g;
#pragma unroll
                    for (int tn = 0; tn < 2; tn++) {
                        int tc = t0 + tn * 16 + lr;
                        sc[tn][g] = __expf(sc[tn][g] * SCALE_ + ((tc > srow) ? -1e9f : 0.f));
                    }
                }
            }
#pragma unroll
            for (int g = 0; g < 4; g++) {
                lpart[g] += sc[0][g] + sc[1][g];
#pragma unroll
                for (int tn = 0; tn < 2; tn++)
                    Ps[(w * 16 + quad * 4 + g) * VSTRIDE + tn * 16 + lr] = f2bf(sc[tn][g]);
            }
            // no barrier: Ps rows are wave-private (write->read same wave)
            bf16x8 pa = *(const bf16x8*)(Ps + (w * 16 + lr) * VSTRIDE + quad * 8);
            __builtin_amdgcn_s_setprio(1);
#pragma unroll
            for (int nt = 0; nt < 8; nt++) {
                bf16x8 vf = *(const bf16x8*)(&Vs[p][(nt * 16 + lr) * VSTRIDE + quad * 8]);
                o[nt] = __builtin_amdgcn_mfma_f32_16x16x32_bf16(pa, vf, o[nt], 0, 0, 0);
            }
            __builtin_amdgcn_s_setprio(0);
        }
    }

#pragma unroll
    for (int g = 0; g < 4; g++) {
        float l = lpart[g];
        l += __shfl_xor(l, 1);
        l += __shfl_xor(l, 2);
        l += __shfl_xor(l, 4);
        l += __shfl_xor(l, 8);
        float inv = 1.f / l;
        int s = q0 + w * 16 + quad * 4 + g;
#pragma unroll
        for (int nt = 0; nt < 8; nt++) {
            int d = nt * 16 + lr;
            att[((size_t)(b * S_ + s)) * D_ + h * HD_ + d] = f2bf(o[nt][g] * inv);
        }
    }
}

extern "C" void kernel_launch(void* const* d_in, const int* in_sizes, int n_in,
                              void* d_out, int out_size, void* d_ws, size_t ws_size,
                              hipStream_t stream)
{
    const float* x  = (const float*)d_in[0];
    const float* Wq = (const float*)d_in[1];
    const float* bq = (const float*)d_in[2];
    const float* Wk = (const float*)d_in[3];
    const float* bk = (const float*)d_in[4];
    const float* Wv = (const float*)d_in[5];
    const float* bv = (const float*)d_in[6];
    const float* Wo = (const float*)d_in[7];
    const float* bo = (const float*)d_in[8];
    const float* fc = (const float*)d_in[9];
    const float* fs = (const float*)d_in[10];
    // d_in[11] (mask): fixed causal mask, analytic. d_in[12] (start_pos): 0.

    const size_t M1 = (size_t)1024 * 1024;
    u16t* ws   = (u16t*)d_ws;
    u16t* x_bf = ws;
    u16t* att  = ws;
    u16t* Wqt  = ws + 16 * M1;
    u16t* Wot  = ws + 16 * M1;
    u16t* Wkt  = ws + 20 * M1;
    u16t* Wvt  = ws + 21 * M1;
    u16t* k_t  = ws + 22 * M1;
    u16t* v_t  = ws + 26 * M1;
    u16t* q_t  = (u16t*)d_out;

    f32_to_bf16<<<dim3(16384), 256, 0, stream>>>(x, x_bf);

    dim3 tb(32, 32);
    transpose_f32_bf16<<<dim3(64, 64), tb, 0, stream>>>(Wq, Wqt, 2048, 2048);
    transpose_f32_bf16<<<dim3(16, 64), tb, 0, stream>>>(Wk, Wkt, 512, 2048);
    transpose_f32_bf16<<<dim3(16, 64), tb, 0, stream>>>(Wv, Wvt, 512, 2048);

    gemm_qkv<<<dim3(24, 64), 256, 0, stream>>>(x_bf, Wqt, bq, bk, bv,
                                               q_t, k_t, v_t, fc, fs);

    attn_kernel<<<dim3(16, 64), 512, 0, stream>>>(q_t, k_t, v_t, att);

    transpose_f32_bf16<<<dim3(64, 64), tb, 0, stream>>>(Wo, Wot, 2048, 2048);

    gemm_o<<<dim3(16, 64), 256, 0, stream>>>(att, Wot, bo, (float*)d_out);
}

// Round 2
// 541.050 us; speedup vs baseline: 1.1223x; 1.0688x over previous
//
#include <hip/hip_runtime.h>

typedef unsigned short u16t;
typedef __bf16 bf16x8 __attribute__((ext_vector_type(8)));
typedef float f32x4 __attribute__((ext_vector_type(4)));
typedef float f32x16 __attribute__((ext_vector_type(16)));
typedef unsigned short ushort4_t __attribute__((ext_vector_type(4)));
typedef unsigned short ushort8_t __attribute__((ext_vector_type(8)));

#define B_    4
#define S_    2048
#define D_    2048
#define H_    16
#define KVH_  4
#define HD_   128
#define KDIM  2048
#define SCALE_ 0.08838834764831845f

__device__ __forceinline__ u16t f2bf(float f){
    unsigned u; __builtin_memcpy(&u, &f, 4);
    u += 0x7fffu + ((u >> 16) & 1u);
    return (u16t)(u >> 16);
}
__device__ __forceinline__ void glds16(const u16t* g, u16t* l){
    __builtin_amdgcn_global_load_lds((const __attribute__((address_space(1))) void*)g,
                                     (__attribute__((address_space(3))) void*)l, 16, 0, 0);
}
// Workgroup barrier WITHOUT the vmcnt(0) drain __syncthreads() would emit.
__device__ __forceinline__ void wg_barrier_lgkm(){
    __builtin_amdgcn_sched_barrier(0);
    asm volatile("s_waitcnt lgkmcnt(0)" ::: "memory");
    __builtin_amdgcn_s_barrier();
    __builtin_amdgcn_sched_barrier(0);
}
__device__ __forceinline__ unsigned cvt_pk_bf16(float lo, float hi){
    unsigned r;
    asm("v_cvt_pk_bf16_f32 %0, %1, %2" : "=v"(r) : "v"(lo), "v"(hi));
    return r;
}
__device__ __forceinline__ void permlane32_swap(unsigned &a, unsigned &b){
    asm volatile("v_permlane32_swap_b32 %0, %1" : "+v"(a), "+v"(b));
}

// ---------------- fp32 -> bf16 convert (x) ----------------
__global__ void f32_to_bf16(const float* __restrict__ in, u16t* __restrict__ out)
{
    int i = (blockIdx.x * 256 + threadIdx.x) * 4;
    float4 v = *(const float4*)(in + i);
    ushort4_t p;
    p[0] = f2bf(v.x); p[1] = f2bf(v.y); p[2] = f2bf(v.z); p[3] = f2bf(v.w);
    *(ushort4_t*)(out + i) = p;
}

// ---------- weight transpose+convert: W(K,N) fp32 -> Wt(N,K) bf16 ----------
__global__ void transpose_f32_bf16(const float* __restrict__ W, u16t* __restrict__ Wt,
                                   int Ncols, int Krows)
{
    __shared__ u16t tile[32][33];
    int tx = threadIdx.x, ty = threadIdx.y;
    int n = blockIdx.x * 32 + tx, k = blockIdx.y * 32 + ty;
    tile[ty][tx] = f2bf(W[(size_t)k * Ncols + n]);
    __syncthreads();
    int nn = blockIdx.x * 32 + ty, kk = blockIdx.y * 32 + tx;
    Wt[(size_t)nn * Krows + kk] = tile[tx][ty];
}

// ============ shared GEMM main loop (128x128 tile, BK=32, m97-style) ============
#define GEMM_PROLOGUE_AND_KLOOP                                                   \
    __shared__ u16t As[128 * 32];                                                 \
    __shared__ u16t Bs[128 * 32];                                                 \
    const int tid  = threadIdx.x;                                                 \
    const int lane = tid & 63, w = tid >> 6;                                      \
    const int wr = (w >> 1) * 64, wc = (w & 1) * 64;                              \
    const int lr = lane & 15, quad = lane >> 4;                                   \
    const int m0 = blockIdx.y * 128, n0 = blockIdx.x * 128;                       \
    f32x4 acc[4][4];                                                              \
    _Pragma("unroll")                                                             \
    for (int r = 0; r < 4; r++)                                                   \
        _Pragma("unroll")                                                         \
        for (int c = 0; c < 4; c++) acc[r][c] = (f32x4){0.f, 0.f, 0.f, 0.f};      \
    for (int k0 = 0; k0 < KDIM; k0 += 32) {                                       \
        __syncthreads();                                                          \
        _Pragma("unroll")                                                         \
        for (int cc = 0; cc < 2; cc++) {                                          \
            int slot = tid + cc * 256;                                            \
            int row = slot >> 2, ko = (slot & 3) * 8;                             \
            glds16(A  + (size_t)(m0 + row) * KDIM + k0 + ko, As + slot * 8);      \
            glds16(Bt + (size_t)(n0 + row) * KDIM + k0 + ko, Bs + slot * 8);      \
        }                                                                         \
        __syncthreads();                                                          \
        bf16x8 a[4], b[4];                                                        \
        _Pragma("unroll")                                                         \
        for (int r = 0; r < 4; r++)                                               \
            a[r] = *(const bf16x8*)(As + (wr + r * 16 + lr) * 32 + quad * 8);     \
        _Pragma("unroll")                                                         \
        for (int c = 0; c < 4; c++)                                               \
            b[c] = *(const bf16x8*)(Bs + (wc + c * 16 + lr) * 32 + quad * 8);     \
        _Pragma("unroll")                                                         \
        for (int r = 0; r < 4; r++)                                               \
            _Pragma("unroll")                                                     \
            for (int c = 0; c < 4; c++)                                           \
                acc[r][c] = __builtin_amdgcn_mfma_f32_16x16x32_bf16(a[r], b[c], acc[r][c], 0, 0, 0); \
    }

// ---------------- O-projection GEMM: fp32 store to d_out ----------------
__global__ void gemm_o(const u16t* __restrict__ A, const u16t* __restrict__ Bt,
                       const float* __restrict__ bias, float* __restrict__ out)
{
    GEMM_PROLOGUE_AND_KLOOP
#pragma unroll
    for (int r = 0; r < 4; r++) {
#pragma unroll
        for (int c = 0; c < 4; c++) {
            int n = n0 + wc + c * 16 + lr;
            float bval = bias[n];
#pragma unroll
            for (int g = 0; g < 4; g++) {
                int m = m0 + wr + r * 16 + quad * 4 + g;
                out[(size_t)m * D_ + n] = acc[r][c][g] + bval;
            }
        }
    }
}

// ---------------- fused QKV GEMM over N=3072 (Bt = [Wqt;Wkt;Wvt]) ------------
__global__ void gemm_qkv(const u16t* __restrict__ A, const u16t* __restrict__ Bt,
                         const float* __restrict__ bq, const float* __restrict__ bk,
                         const float* __restrict__ bv,
                         u16t* __restrict__ q_t, u16t* __restrict__ k_t,
                         u16t* __restrict__ v_t,
                         const float* __restrict__ fc, const float* __restrict__ fs)
{
    GEMM_PROLOGUE_AND_KLOOP
    const int region = (blockIdx.x < 16) ? 0 : ((blockIdx.x < 20) ? 1 : 2);
#pragma unroll
    for (int r = 0; r < 4; r++) {
#pragma unroll
        for (int c = 0; c < 4; c++) {
            int n = n0 + wc + c * 16 + lr;
            if (region == 0) {          // Q + RoPE
                float bval = bq[n];
                int hh = n >> 7, d = n & 127, i2 = d >> 1;
#pragma unroll
                for (int g = 0; g < 4; g++) {
                    int m = m0 + wr + r * 16 + quad * 4 + g;
                    int bb = m >> 11, s = m & (S_ - 1);
                    float v = acc[r][c][g] + bval;
                    float p = __shfl_xor(v, 1);
                    float cf = fc[s * 64 + i2], sf = fs[s * 64 + i2];
                    float o = (d & 1) ? (p * sf + v * cf) : (v * cf - p * sf);
                    q_t[(((size_t)bb * H_ + hh) * S_ + s) * HD_ + d] = f2bf(o);
                }
            } else if (region == 1) {   // K + RoPE
                int nk = n - 2048;
                float bval = bk[nk];
                int hh = nk >> 7, d = nk & 127, i2 = d >> 1;
#pragma unroll
                for (int g = 0; g < 4; g++) {
                    int m = m0 + wr + r * 16 + quad * 4 + g;
                    int bb = m >> 11, s = m & (S_ - 1);
                    float v = acc[r][c][g] + bval;
                    float p = __shfl_xor(v, 1);
                    float cf = fc[s * 64 + i2], sf = fs[s * 64 + i2];
                    float o = (d & 1) ? (p * sf + v * cf) : (v * cf - p * sf);
                    k_t[(((size_t)bb * KVH_ + hh) * S_ + s) * HD_ + d] = f2bf(o);
                }
            } else {                    // V transposed
                int nv = n - 2560;
                float bval = bv[nv];
                int kv = nv >> 7, d = nv & 127;
                int mb = m0 + wr + r * 16 + quad * 4;
                int bb = mb >> 11, s = mb & (S_ - 1);
                ushort4_t pk;
#pragma unroll
                for (int g = 0; g < 4; g++) pk[g] = f2bf(acc[r][c][g] + bval);
                *(ushort4_t*)(v_t + (((size_t)bb * KVH_ + kv) * HD_ + d) * S_ + s) = pk;
            }
        }
    }
}

// ---------------- flash attention, causal, GQA (bf16 in/out) ----------------
// 4 waves x 32 q-rows (32x32x16 MFMA): halves LDS fragment traffic per FLOP.
// Swapped QK^T (mfma(K,Q)) makes q-row lane-local -> P goes to PV A-frags
// in-register via cvt_pk_bf16 + permlane32_swap (no Ps LDS at all).
// K tile [32][128] bf16 (256 B rows) XOR-swz byte^=((row&7)<<4);
// V^T tile [128][32] bf16 (64 B rows) XOR-swz byte^=(((d>>1)&3)<<5).
// Both give exactly 8 16B-chunks per bank-slot per wave64 access (= minimum).
// Reg-staged K/V double buffer, lgkm-only barrier, prefetch depth 2.
__global__ __launch_bounds__(256, 2) void
attn_kernel(const u16t* __restrict__ qt, const u16t* __restrict__ kt,
            const u16t* __restrict__ vt, u16t* __restrict__ att)
{
    __shared__ char Ks[2][8192];
    __shared__ char Vs[2][8192];
    const int tid  = threadIdx.x;
    const int lane = tid & 63, w = tid >> 6;          // w 0..3
    const int l5 = lane & 31, hi = lane >> 5;
    const int bh = blockIdx.y, b = bh >> 4, h = bh & 15, kv = h >> 2;
    const int q0 = ((int)gridDim.x - 1 - (int)blockIdx.x) * 128;  // heavy blocks first

    const u16t* qb = qt + (((size_t)b * H_ + h) * S_ + q0) * HD_;
    const u16t* kb = kt + ((size_t)b * KVH_ + kv) * S_ * HD_;
    const u16t* vb = vt + ((size_t)b * KVH_ + kv) * HD_ * S_;

    // Q fragments (B-operand): col q = w*32+l5, k = ks*16 + hi*8 + e
    bf16x8 qa[8];
#pragma unroll
    for (int ks = 0; ks < 8; ks++)
        qa[ks] = *(const bf16x8*)(qb + (w * 32 + l5) * HD_ + ks * 16 + hi * 8);

    f32x16 zero16;
#pragma unroll
    for (int j = 0; j < 16; j++) zero16[j] = 0.f;
    f32x16 o[4];
#pragma unroll
    for (int i = 0; i < 4; i++) o[i] = zero16;
    float lpart = 0.f;

    // staging decomposition (256 threads, 2 granules of 16B per tensor each)
    const int krow = tid >> 4, kcol = tid & 15;   // K: 32 rows x 16 col-chunks
    const int vd   = tid >> 2, vcol = tid & 3;    // V^T: 128 rows x 4 t-chunks
    const int kw0 = ((krow     ) * 256 + kcol * 16) ^ ((krow & 7) << 4);
    const int kw1 = ((krow + 16) * 256 + kcol * 16) ^ ((krow & 7) << 4);
    const int vw0 = ((vd      ) * 64 + vcol * 16) ^ (((vd >> 1) & 3) << 5);
    const int vw1 = ((vd + 64 ) * 64 + vcol * 16) ^ (((vd >> 1) & 3) << 5);

    const int ntile = q0 / 32 + 4;   // even
    ushort8_t kr[2][2], vr[2][2];
#pragma unroll
    for (int p = 0; p < 2; p++) {
        int t0 = p * 32;
        kr[p][0] = *(const ushort8_t*)(kb + (size_t)(t0 + krow     ) * HD_ + kcol * 8);
        kr[p][1] = *(const ushort8_t*)(kb + (size_t)(t0 + krow + 16) * HD_ + kcol * 8);
        vr[p][0] = *(const ushort8_t*)(vb + (size_t)(vd     ) * S_ + t0 + vcol * 8);
        vr[p][1] = *(const ushort8_t*)(vb + (size_t)(vd + 64) * S_ + t0 + vcol * 8);
    }

    for (int it = 0; it < ntile; it += 2) {
#pragma unroll
        for (int p = 0; p < 2; p++) {
            const int t0 = (it + p) * 32;
            // stage prefetched regs -> LDS buffer p (swizzled writes)
            *(ushort8_t*)(Ks[p] + kw0) = kr[p][0];
            *(ushort8_t*)(Ks[p] + kw1) = kr[p][1];
            *(ushort8_t*)(Vs[p] + vw0) = vr[p][0];
            *(ushort8_t*)(Vs[p] + vw1) = vr[p][1];
            // prefetch tile it+p+2 (clamped; tail reloads tile 0 harmlessly)
            const int tn0 = (it + p + 2 < ntile) ? (it + p + 2) * 32 : 0;
            kr[p][0] = *(const ushort8_t*)(kb + (size_t)(tn0 + krow     ) * HD_ + kcol * 8);
            kr[p][1] = *(const ushort8_t*)(kb + (size_t)(tn0 + krow + 16) * HD_ + kcol * 8);
            vr[p][0] = *(const ushort8_t*)(vb + (size_t)(vd     ) * S_ + tn0 + vcol * 8);
            vr[p][1] = *(const ushort8_t*)(vb + (size_t)(vd + 64) * S_ + tn0 + vcol * 8);
            wg_barrier_lgkm();   // LDS visible; global prefetch stays in flight

            if (t0 > q0 + w * 32 + 31) continue;   // tile fully masked for this wave

            // QK^T swapped: sc[r] = S[kv = t0 + (r&3)+8*(r>>2)+4*hi][q = q0+w*32+l5]
            f32x16 sa = zero16, sb = zero16;
            __builtin_amdgcn_s_setprio(1);
#pragma unroll
            for (int ks = 0; ks < 8; ks += 2) {
                bf16x8 kf0 = *(const bf16x8*)(Ks[p] +
                    ((l5 * 256 + ks * 32 + hi * 16) ^ ((l5 & 7) << 4)));
                sa = __builtin_amdgcn_mfma_f32_32x32x16_bf16(kf0, qa[ks], sa, 0, 0, 0);
                bf16x8 kf1 = *(const bf16x8*)(Ks[p] +
                    ((l5 * 256 + (ks + 1) * 32 + hi * 16) ^ ((l5 & 7) << 4)));
                sb = __builtin_amdgcn_mfma_f32_32x32x16_bf16(kf1, qa[ks + 1], sb, 0, 0, 0);
            }
            __builtin_amdgcn_s_setprio(0);
            f32x16 sc = sa + sb;

            float pr[16];
            if (t0 + 31 <= q0 + w * 32) {            // fully unmasked for this wave
#pragma unroll
                for (int r = 0; r < 16; r++) pr[r] = __expf(sc[r] * SCALE_);
            } else {
                const int srow = q0 + w * 32 + l5;
#pragma unroll
                for (int r = 0; r < 16; r++) {
                    int tc = t0 + (r & 3) + 8 * (r >> 2) + 4 * hi;
                    pr[r] = __expf(sc[r] * SCALE_ + ((tc > srow) ? -1e9f : 0.f));
                }
            }
#pragma unroll
            for (int r = 0; r < 16; r++) lpart += pr[r];

            // pack P -> PV A-fragments entirely in-register
            unsigned d0[4], d1[4];
#pragma unroll
            for (int q4 = 0; q4 < 4; q4++) {
                d0[q4] = cvt_pk_bf16(pr[4 * q4 + 0], pr[4 * q4 + 1]);
                d1[q4] = cvt_pk_bf16(pr[4 * q4 + 2], pr[4 * q4 + 3]);
            }
            permlane32_swap(d0[0], d0[1]);
            permlane32_swap(d1[0], d1[1]);
            permlane32_swap(d0[2], d0[3]);
            permlane32_swap(d1[2], d1[3]);
            union { unsigned u[4]; bf16x8 v; } pa0, pa1;
            pa0.u[0] = d0[0]; pa0.u[1] = d1[0]; pa0.u[2] = d0[1]; pa0.u[3] = d1[1];
            pa1.u[0] = d0[2]; pa1.u[1] = d1[2]; pa1.u[2] = d0[3]; pa1.u[3] = d1[3];

            __builtin_amdgcn_s_setprio(1);
#pragma unroll
            for (int dt = 0; dt < 4; dt++) {
                bf16x8 vf0 = *(const bf16x8*)(Vs[p] +
                    (((dt * 32 + l5) * 64 + hi * 16) ^ (((l5 >> 1) & 3) << 5)));
                o[dt] = __builtin_amdgcn_mfma_f32_32x32x16_bf16(pa0.v, vf0, o[dt], 0, 0, 0);
                bf16x8 vf1 = *(const bf16x8*)(Vs[p] +
                    (((dt * 32 + l5) * 64 + 32 + hi * 16) ^ (((l5 >> 1) & 3) << 5)));
                o[dt] = __builtin_amdgcn_mfma_f32_32x32x16_bf16(pa1.v, vf1, o[dt], 0, 0, 0);
            }
            __builtin_amdgcn_s_setprio(0);
        }
    }

    // epilogue: finish row sums (halves hold disjoint kv subsets), normalize, store
    float lf = lpart + __shfl_xor(lpart, 32);
    float linv = 1.f / lf;                       // valid for q-row = l5 (both halves)
#pragma unroll
    for (int r = 0; r < 16; r++) {
        int qrow = (r & 3) + 8 * (r >> 2) + 4 * hi;
        float iv = __shfl(linv, qrow);
        int s = q0 + w * 32 + qrow;
        u16t* orow = att + ((size_t)(b * S_ + s)) * D_ + h * HD_ + l5;
#pragma unroll
        for (int dt = 0; dt < 4; dt++)
            orow[dt * 32] = f2bf(o[dt][r] * iv);
    }
}

extern "C" void kernel_launch(void* const* d_in, const int* in_sizes, int n_in,
                              void* d_out, int out_size, void* d_ws, size_t ws_size,
                              hipStream_t stream)
{
    const float* x  = (const float*)d_in[0];
    const float* Wq = (const float*)d_in[1];
    const float* bq = (const float*)d_in[2];
    const float* Wk = (const float*)d_in[3];
    const float* bk = (const float*)d_in[4];
    const float* Wv = (const float*)d_in[5];
    const float* bv = (const float*)d_in[6];
    const float* Wo = (const float*)d_in[7];
    const float* bo = (const float*)d_in[8];
    const float* fc = (const float*)d_in[9];
    const float* fs = (const float*)d_in[10];
    // d_in[11] (mask): fixed causal mask, analytic. d_in[12] (start_pos): 0.

    const size_t M1 = (size_t)1024 * 1024;
    u16t* ws   = (u16t*)d_ws;
    u16t* x_bf = ws;
    u16t* att  = ws;
    u16t* Wqt  = ws + 16 * M1;
    u16t* Wot  = ws + 16 * M1;
    u16t* Wkt  = ws + 20 * M1;
    u16t* Wvt  = ws + 21 * M1;
    u16t* k_t  = ws + 22 * M1;
    u16t* v_t  = ws + 26 * M1;
    u16t* q_t  = (u16t*)d_out;

    f32_to_bf16<<<dim3(16384), 256, 0, stream>>>(x, x_bf);

    dim3 tb(32, 32);
    transpose_f32_bf16<<<dim3(64, 64), tb, 0, stream>>>(Wq, Wqt, 2048, 2048);
    transpose_f32_bf16<<<dim3(16, 64), tb, 0, stream>>>(Wk, Wkt, 512, 2048);
    transpose_f32_bf16<<<dim3(16, 64), tb, 0, stream>>>(Wv, Wvt, 512, 2048);

    gemm_qkv<<<dim3(24, 64), 256, 0, stream>>>(x_bf, Wqt, bq, bk, bv,
                                               q_t, k_t, v_t, fc, fs);

    attn_kernel<<<dim3(16, 64), 256, 0, stream>>>(q_t, k_t, v_t, att);

    transpose_f32_bf16<<<dim3(64, 64), tb, 0, stream>>>(Wo, Wot, 2048, 2048);

    gemm_o<<<dim3(16, 64), 256, 0, stream>>>(att, Wot, bo, (float*)d_out);
}

// Round 5
// 487.217 us; speedup vs baseline: 1.2463x; 1.1105x over previous
//
#include <hip/hip_runtime.h>

typedef unsigned short u16t;
typedef __bf16 bf16x8 __attribute__((ext_vector_type(8)));
typedef float f32x4 __attribute__((ext_vector_type(4)));
typedef float f32x16 __attribute__((ext_vector_type(16)));
typedef unsigned short ushort4_t __attribute__((ext_vector_type(4)));
typedef unsigned short ushort8_t __attribute__((ext_vector_type(8)));

#define B_    4
#define S_    2048
#define D_    2048
#define H_    16
#define KVH_  4
#define HD_   128
#define KDIM  2048
#define SCALE_ 0.08838834764831845f

__device__ __forceinline__ u16t f2bf(float f){
    unsigned u; __builtin_memcpy(&u, &f, 4);
    u += 0x7fffu + ((u >> 16) & 1u);
    return (u16t)(u >> 16);
}
__device__ __forceinline__ void glds16(const u16t* g, u16t* l){
    __builtin_amdgcn_global_load_lds((const __attribute__((address_space(1))) void*)g,
                                     (__attribute__((address_space(3))) void*)l, 16, 0, 0);
}
// Workgroup barrier WITHOUT the vmcnt(0) drain __syncthreads() would emit.
__device__ __forceinline__ void wg_barrier_lgkm(){
    __builtin_amdgcn_sched_barrier(0);
    asm volatile("s_waitcnt lgkmcnt(0)" ::: "memory");
    __builtin_amdgcn_s_barrier();
    __builtin_amdgcn_sched_barrier(0);
}
__device__ __forceinline__ unsigned cvt_pk_bf16(float lo, float hi){
    unsigned r;
    asm("v_cvt_pk_bf16_f32 %0, %1, %2" : "=v"(r) : "v"(lo), "v"(hi));
    return r;
}
__device__ __forceinline__ void permlane32_swap(unsigned &a, unsigned &b){
    asm volatile("v_permlane32_swap_b32 %0, %1" : "+v"(a), "+v"(b));
}

// ---------------- fp32 -> bf16 convert (x) ----------------
__global__ void f32_to_bf16(const float* __restrict__ in, u16t* __restrict__ out)
{
    int i = (blockIdx.x * 256 + threadIdx.x) * 4;
    float4 v = *(const float4*)(in + i);
    ushort4_t p;
    p[0] = f2bf(v.x); p[1] = f2bf(v.y); p[2] = f2bf(v.z); p[3] = f2bf(v.w);
    *(ushort4_t*)(out + i) = p;
}

// ---------- weight transpose+convert: W(K,N) fp32 -> Wt(N,K) bf16 ----------
__global__ void transpose_f32_bf16(const float* __restrict__ W, u16t* __restrict__ Wt,
                                   int Ncols, int Krows)
{
    __shared__ u16t tile[32][33];
    int tx = threadIdx.x, ty = threadIdx.y;
    int n = blockIdx.x * 32 + tx, k = blockIdx.y * 32 + ty;
    tile[ty][tx] = f2bf(W[(size_t)k * Ncols + n]);
    __syncthreads();
    int nn = blockIdx.x * 32 + ty, kk = blockIdx.y * 32 + tx;
    Wt[(size_t)nn * Krows + kk] = tile[tx][ty];
}

// ============ shared GEMM main loop (128x128 tile, BK=32, m97-style) ============
#define GEMM_PROLOGUE_AND_KLOOP                                                   \
    __shared__ u16t As[128 * 32];                                                 \
    __shared__ u16t Bs[128 * 32];                                                 \
    const int tid  = threadIdx.x;                                                 \
    const int lane = tid & 63, w = tid >> 6;                                      \
    const int wr = (w >> 1) * 64, wc = (w & 1) * 64;                              \
    const int lr = lane & 15, quad = lane >> 4;                                   \
    const int m0 = blockIdx.y * 128, n0 = blockIdx.x * 128;                       \
    f32x4 acc[4][4];                                                              \
    _Pragma("unroll")                                                             \
    for (int r = 0; r < 4; r++)                                                   \
        _Pragma("unroll")                                                         \
        for (int c = 0; c < 4; c++) acc[r][c] = (f32x4){0.f, 0.f, 0.f, 0.f};      \
    for (int k0 = 0; k0 < KDIM; k0 += 32) {                                       \
        __syncthreads();                                                          \
        _Pragma("unroll")                                                         \
        for (int cc = 0; cc < 2; cc++) {                                          \
            int slot = tid + cc * 256;                                            \
            int row = slot >> 2, ko = (slot & 3) * 8;                             \
            glds16(A  + (size_t)(m0 + row) * KDIM + k0 + ko, As + slot * 8);      \
            glds16(Bt + (size_t)(n0 + row) * KDIM + k0 + ko, Bs + slot * 8);      \
        }                                                                         \
        __syncthreads();                                                          \
        bf16x8 a[4], b[4];                                                        \
        _Pragma("unroll")                                                         \
        for (int r = 0; r < 4; r++)                                               \
            a[r] = *(const bf16x8*)(As + (wr + r * 16 + lr) * 32 + quad * 8);     \
        _Pragma("unroll")                                                         \
        for (int c = 0; c < 4; c++)                                               \
            b[c] = *(const bf16x8*)(Bs + (wc + c * 16 + lr) * 32 + quad * 8);     \
        _Pragma("unroll")                                                         \
        for (int r = 0; r < 4; r++)                                               \
            _Pragma("unroll")                                                     \
            for (int c = 0; c < 4; c++)                                           \
                acc[r][c] = __builtin_amdgcn_mfma_f32_16x16x32_bf16(a[r], b[c], acc[r][c], 0, 0, 0); \
    }

// ---------------- O-projection GEMM: fp32 store to d_out ----------------
__global__ void gemm_o(const u16t* __restrict__ A, const u16t* __restrict__ Bt,
                       const float* __restrict__ bias, float* __restrict__ out)
{
    GEMM_PROLOGUE_AND_KLOOP
#pragma unroll
    for (int r = 0; r < 4; r++) {
#pragma unroll
        for (int c = 0; c < 4; c++) {
            int n = n0 + wc + c * 16 + lr;
            float bval = bias[n];
#pragma unroll
            for (int g = 0; g < 4; g++) {
                int m = m0 + wr + r * 16 + quad * 4 + g;
                out[(size_t)m * D_ + n] = acc[r][c][g] + bval;
            }
        }
    }
}

// ---------------- fused QKV GEMM over N=3072 (Bt = [Wqt;Wkt;Wvt]) ------------
__global__ void gemm_qkv(const u16t* __restrict__ A, const u16t* __restrict__ Bt,
                         const float* __restrict__ bq, const float* __restrict__ bk,
                         const float* __restrict__ bv,
                         u16t* __restrict__ q_t, u16t* __restrict__ k_t,
                         u16t* __restrict__ v_t,
                         const float* __restrict__ fc, const float* __restrict__ fs)
{
    GEMM_PROLOGUE_AND_KLOOP
    const int region = (blockIdx.x < 16) ? 0 : ((blockIdx.x < 20) ? 1 : 2);
#pragma unroll
    for (int r = 0; r < 4; r++) {
#pragma unroll
        for (int c = 0; c < 4; c++) {
            int n = n0 + wc + c * 16 + lr;
            if (region == 0) {          // Q + RoPE
                float bval = bq[n];
                int hh = n >> 7, d = n & 127, i2 = d >> 1;
#pragma unroll
                for (int g = 0; g < 4; g++) {
                    int m = m0 + wr + r * 16 + quad * 4 + g;
                    int bb = m >> 11, s = m & (S_ - 1);
                    float v = acc[r][c][g] + bval;
                    float p = __shfl_xor(v, 1);
                    float cf = fc[s * 64 + i2], sf = fs[s * 64 + i2];
                    float o = (d & 1) ? (p * sf + v * cf) : (v * cf - p * sf);
                    q_t[(((size_t)bb * H_ + hh) * S_ + s) * HD_ + d] = f2bf(o);
                }
            } else if (region == 1) {   // K + RoPE
                int nk = n - 2048;
                float bval = bk[nk];
                int hh = nk >> 7, d = nk & 127, i2 = d >> 1;
#pragma unroll
                for (int g = 0; g < 4; g++) {
                    int m = m0 + wr + r * 16 + quad * 4 + g;
                    int bb = m >> 11, s = m & (S_ - 1);
                    float v = acc[r][c][g] + bval;
                    float p = __shfl_xor(v, 1);
                    float cf = fc[s * 64 + i2], sf = fs[s * 64 + i2];
                    float o = (d & 1) ? (p * sf + v * cf) : (v * cf - p * sf);
                    k_t[(((size_t)bb * KVH_ + hh) * S_ + s) * HD_ + d] = f2bf(o);
                }
            } else {                    // V transposed
                int nv = n - 2560;
                float bval = bv[nv];
                int kv = nv >> 7, d = nv & 127;
                int mb = m0 + wr + r * 16 + quad * 4;
                int bb = mb >> 11, s = mb & (S_ - 1);
                ushort4_t pk;
#pragma unroll
                for (int g = 0; g < 4; g++) pk[g] = f2bf(acc[r][c][g] + bval);
                *(ushort4_t*)(v_t + (((size_t)bb * KVH_ + kv) * HD_ + d) * S_ + s) = pk;
            }
        }
    }
}

// ---------------- flash attention, causal, GQA (bf16 in/out) ----------------
// 4 waves x 32 q-rows, 32x32x16 MFMA, swapped QK^T, in-register P (cvt_pk +
// permlane32_swap), XOR-swizzled K/V LDS, reg-staged double buffer,
// lgkm-only barrier. q-tile PAIRING for perfect causal balance —
// each block processes q-tiles (15-bx) then (bx): every block = 68 phases,
// grid (8,64)=512 blocks = exactly 2 equal blocks/CU, no dispatch tail.
// seg loop pinned to unroll 1 to keep code size == round-2 build.
__global__ __launch_bounds__(256, 2) void
attn_kernel(const u16t* __restrict__ qt, const u16t* __restrict__ kt,
            const u16t* __restrict__ vt, u16t* __restrict__ att)
{
    __shared__ char Ks[2][8192];
    __shared__ char Vs[2][8192];
    const int tid  = threadIdx.x;
    const int lane = tid & 63, w = tid >> 6;          // w 0..3
    const int l5 = lane & 31, hi = lane >> 5;
    const int bh = blockIdx.y, b = bh >> 4, h = bh & 15, kv = h >> 2;
    const int bx = blockIdx.x;                        // 0..7

    const u16t* kb = kt + ((size_t)b * KVH_ + kv) * S_ * HD_;
    const u16t* vb = vt + ((size_t)b * KVH_ + kv) * HD_ * S_;

    f32x16 zero16;
#pragma unroll
    for (int j = 0; j < 16; j++) zero16[j] = 0.f;

    // staging decomposition (256 threads, 2 granules of 16B per tensor each)
    const int krow = tid >> 4, kcol = tid & 15;   // K: 32 rows x 16 col-chunks
    const int vd   = tid >> 2, vcol = tid & 3;    // V^T: 128 rows x 4 t-chunks
    const int kw0 = ((krow     ) * 256 + kcol * 16) ^ ((krow & 7) << 4);
    const int kw1 = ((krow + 16) * 256 + kcol * 16) ^ ((krow & 7) << 4);
    const int vw0 = ((vd      ) * 64 + vcol * 16) ^ (((vd >> 1) & 3) << 5);
    const int vw1 = ((vd + 64 ) * 64 + vcol * 16) ^ (((vd >> 1) & 3) << 5);

    ushort8_t kr[2][2], vr[2][2];

#pragma unroll 1
    for (int seg = 0; seg < 2; seg++) {
        const int q0 = (seg == 0 ? (15 - bx) : bx) * 128;   // heavy tile first
        const u16t* qb = qt + (((size_t)b * H_ + h) * S_ + q0) * HD_;

        // Q fragments (B-operand): col q = w*32+l5, k = ks*16 + hi*8 + e
        bf16x8 qa[8];
#pragma unroll
        for (int ks = 0; ks < 8; ks++)
            qa[ks] = *(const bf16x8*)(qb + (w * 32 + l5) * HD_ + ks * 16 + hi * 8);

        f32x16 o[4];
#pragma unroll
        for (int i = 0; i < 4; i++) o[i] = zero16;
        float lpart = 0.f;

        const int ntile = q0 / 32 + 4;   // even
#pragma unroll
        for (int p = 0; p < 2; p++) {
            int t0 = p * 32;
            kr[p][0] = *(const ushort8_t*)(kb + (size_t)(t0 + krow     ) * HD_ + kcol * 8);
            kr[p][1] = *(const ushort8_t*)(kb + (size_t)(t0 + krow + 16) * HD_ + kcol * 8);
            vr[p][0] = *(const ushort8_t*)(vb + (size_t)(vd     ) * S_ + t0 + vcol * 8);
            vr[p][1] = *(const ushort8_t*)(vb + (size_t)(vd + 64) * S_ + t0 + vcol * 8);
        }

        for (int it = 0; it < ntile; it += 2) {
#pragma unroll
            for (int p = 0; p < 2; p++) {
                const int t0 = (it + p) * 32;
                // stage prefetched regs -> LDS buffer p (swizzled writes)
                *(ushort8_t*)(Ks[p] + kw0) = kr[p][0];
                *(ushort8_t*)(Ks[p] + kw1) = kr[p][1];
                *(ushort8_t*)(Vs[p] + vw0) = vr[p][0];
                *(ushort8_t*)(Vs[p] + vw1) = vr[p][1];
                // prefetch tile it+p+2 (clamped; tail reloads tile 0 harmlessly)
                const int tn0 = (it + p + 2 < ntile) ? (it + p + 2) * 32 : 0;
                kr[p][0] = *(const ushort8_t*)(kb + (size_t)(tn0 + krow     ) * HD_ + kcol * 8);
                kr[p][1] = *(const ushort8_t*)(kb + (size_t)(tn0 + krow + 16) * HD_ + kcol * 8);
                vr[p][0] = *(const ushort8_t*)(vb + (size_t)(vd     ) * S_ + tn0 + vcol * 8);
                vr[p][1] = *(const ushort8_t*)(vb + (size_t)(vd + 64) * S_ + tn0 + vcol * 8);
                wg_barrier_lgkm();   // LDS visible; global prefetch stays in flight

                if (t0 > q0 + w * 32 + 31) continue;   // tile fully masked for this wave

                // QK^T swapped: sc[r] = S[kv = t0 + (r&3)+8*(r>>2)+4*hi][q = q0+w*32+l5]
                f32x16 sa = zero16, sb = zero16;
                __builtin_amdgcn_s_setprio(1);
#pragma unroll
                for (int ks = 0; ks < 8; ks += 2) {
                    bf16x8 kf0 = *(const bf16x8*)(Ks[p] +
                        ((l5 * 256 + ks * 32 + hi * 16) ^ ((l5 & 7) << 4)));
                    sa = __builtin_amdgcn_mfma_f32_32x32x16_bf16(kf0, qa[ks], sa, 0, 0, 0);
                    bf16x8 kf1 = *(const bf16x8*)(Ks[p] +
                        ((l5 * 256 + (ks + 1) * 32 + hi * 16) ^ ((l5 & 7) << 4)));
                    sb = __builtin_amdgcn_mfma_f32_32x32x16_bf16(kf1, qa[ks + 1], sb, 0, 0, 0);
                }
                __builtin_amdgcn_s_setprio(0);
                f32x16 sc = sa + sb;

                float pr[16];
                if (t0 + 31 <= q0 + w * 32) {            // fully unmasked for this wave
#pragma unroll
                    for (int r = 0; r < 16; r++) pr[r] = __expf(sc[r] * SCALE_);
                } else {
                    const int srow = q0 + w * 32 + l5;
#pragma unroll
                    for (int r = 0; r < 16; r++) {
                        int tc = t0 + (r & 3) + 8 * (r >> 2) + 4 * hi;
                        pr[r] = __expf(sc[r] * SCALE_ + ((tc > srow) ? -1e9f : 0.f));
                    }
                }
#pragma unroll
                for (int r = 0; r < 16; r++) lpart += pr[r];

                // pack P -> PV A-fragments entirely in-register
                unsigned d0[4], d1[4];
#pragma unroll
                for (int q4 = 0; q4 < 4; q4++) {
                    d0[q4] = cvt_pk_bf16(pr[4 * q4 + 0], pr[4 * q4 + 1]);
                    d1[q4] = cvt_pk_bf16(pr[4 * q4 + 2], pr[4 * q4 + 3]);
                }
                permlane32_swap(d0[0], d0[1]);
                permlane32_swap(d1[0], d1[1]);
                permlane32_swap(d0[2], d0[3]);
                permlane32_swap(d1[2], d1[3]);
                union { unsigned u[4]; bf16x8 v; } pa0, pa1;
                pa0.u[0] = d0[0]; pa0.u[1] = d1[0]; pa0.u[2] = d0[1]; pa0.u[3] = d1[1];
                pa1.u[0] = d0[2]; pa1.u[1] = d1[2]; pa1.u[2] = d0[3]; pa1.u[3] = d1[3];

                __builtin_amdgcn_s_setprio(1);
#pragma unroll
                for (int dt = 0; dt < 4; dt++) {
                    bf16x8 vf0 = *(const bf16x8*)(Vs[p] +
                        (((dt * 32 + l5) * 64 + hi * 16) ^ (((l5 >> 1) & 3) << 5)));
                    o[dt] = __builtin_amdgcn_mfma_f32_32x32x16_bf16(pa0.v, vf0, o[dt], 0, 0, 0);
                    bf16x8 vf1 = *(const bf16x8*)(Vs[p] +
                        (((dt * 32 + l5) * 64 + 32 + hi * 16) ^ (((l5 >> 1) & 3) << 5)));
                    o[dt] = __builtin_amdgcn_mfma_f32_32x32x16_bf16(pa1.v, vf1, o[dt], 0, 0, 0);
                }
                __builtin_amdgcn_s_setprio(0);
            }
        }

        // epilogue: finish row sums (halves hold disjoint kv subsets), normalize, store
        float lf = lpart + __shfl_xor(lpart, 32);
        float linv = 1.f / lf;                       // valid for q-row = l5 (both halves)
#pragma unroll
        for (int r = 0; r < 16; r++) {
            int qrow = (r & 3) + 8 * (r >> 2) + 4 * hi;
            float iv = __shfl(linv, qrow);
            int s = q0 + w * 32 + qrow;
            u16t* orow = att + ((size_t)(b * S_ + s)) * D_ + h * HD_ + l5;
#pragma unroll
            for (int dt = 0; dt < 4; dt++)
                orow[dt * 32] = f2bf(o[dt][r] * iv);
        }
    }
}

extern "C" void kernel_launch(void* const* d_in, const int* in_sizes, int n_in,
                              void* d_out, int out_size, void* d_ws, size_t ws_size,
                              hipStream_t stream)
{
    const float* x  = (const float*)d_in[0];
    const float* Wq = (const float*)d_in[1];
    const float* bq = (const float*)d_in[2];
    const float* Wk = (const float*)d_in[3];
    const float* bk = (const float*)d_in[4];
    const float* Wv = (const float*)d_in[5];
    const float* bv = (const float*)d_in[6];
    const float* Wo = (const float*)d_in[7];
    const float* bo = (const float*)d_in[8];
    const float* fc = (const float*)d_in[9];
    const float* fs = (const float*)d_in[10];
    // d_in[11] (mask): fixed causal mask, analytic. d_in[12] (start_pos): 0.

    const size_t M1 = (size_t)1024 * 1024;
    u16t* ws   = (u16t*)d_ws;
    u16t* x_bf = ws;
    u16t* att  = ws;
    u16t* Wqt  = ws + 16 * M1;
    u16t* Wot  = ws + 16 * M1;
    u16t* Wkt  = ws + 20 * M1;
    u16t* Wvt  = ws + 21 * M1;
    u16t* k_t  = ws + 22 * M1;
    u16t* v_t  = ws + 26 * M1;
    u16t* q_t  = (u16t*)d_out;

    f32_to_bf16<<<dim3(16384), 256, 0, stream>>>(x, x_bf);

    dim3 tb(32, 32);
    transpose_f32_bf16<<<dim3(64, 64), tb, 0, stream>>>(Wq, Wqt, 2048, 2048);
    transpose_f32_bf16<<<dim3(16, 64), tb, 0, stream>>>(Wk, Wkt, 512, 2048);
    transpose_f32_bf16<<<dim3(16, 64), tb, 0, stream>>>(Wv, Wvt, 512, 2048);

    gemm_qkv<<<dim3(24, 64), 256, 0, stream>>>(x_bf, Wqt, bq, bk, bv,
                                               q_t, k_t, v_t, fc, fs);

    attn_kernel<<<dim3(8, 64), 256, 0, stream>>>(q_t, k_t, v_t, att);

    transpose_f32_bf16<<<dim3(64, 64), tb, 0, stream>>>(Wo, Wot, 2048, 2048);

    gemm_o<<<dim3(16, 64), 256, 0, stream>>>(att, Wot, bo, (float*)d_out);
}

// Round 6
// 465.038 us; speedup vs baseline: 1.3057x; 1.0477x over previous
//
#include <hip/hip_runtime.h>

typedef unsigned short u16t;
typedef __bf16 bf16x8 __attribute__((ext_vector_type(8)));
typedef float f32x4 __attribute__((ext_vector_type(4)));
typedef float f32x16 __attribute__((ext_vector_type(16)));
typedef unsigned short ushort4_t __attribute__((ext_vector_type(4)));
typedef unsigned short ushort8_t __attribute__((ext_vector_type(8)));

#define B_    4
#define S_    2048
#define D_    2048
#define H_    16
#define KVH_  4
#define HD_   128
#define KDIM  2048
#define SCALE_ 0.08838834764831845f

__device__ __forceinline__ u16t f2bf(float f){
    unsigned u; __builtin_memcpy(&u, &f, 4);
    u += 0x7fffu + ((u >> 16) & 1u);
    return (u16t)(u >> 16);
}
__device__ __forceinline__ void glds16(const u16t* g, u16t* l){
    __builtin_amdgcn_global_load_lds((const __attribute__((address_space(1))) void*)g,
                                     (__attribute__((address_space(3))) void*)l, 16, 0, 0);
}
// Workgroup barrier WITHOUT the vmcnt(0) drain __syncthreads() would emit.
__device__ __forceinline__ void wg_barrier_lgkm(){
    __builtin_amdgcn_sched_barrier(0);
    asm volatile("s_waitcnt lgkmcnt(0)" ::: "memory");
    __builtin_amdgcn_s_barrier();
    __builtin_amdgcn_sched_barrier(0);
}
__device__ __forceinline__ unsigned cvt_pk_bf16(float lo, float hi){
    unsigned r;
    asm("v_cvt_pk_bf16_f32 %0, %1, %2" : "=v"(r) : "v"(lo), "v"(hi));
    return r;
}
__device__ __forceinline__ void permlane32_swap(unsigned &a, unsigned &b){
    asm volatile("v_permlane32_swap_b32 %0, %1" : "+v"(a), "+v"(b));
}

// ---------------- fp32 -> bf16 convert (x) ----------------
__global__ void f32_to_bf16(const float* __restrict__ in, u16t* __restrict__ out)
{
    int i = (blockIdx.x * 256 + threadIdx.x) * 4;
    float4 v = *(const float4*)(in + i);
    ushort4_t p;
    p[0] = f2bf(v.x); p[1] = f2bf(v.y); p[2] = f2bf(v.z); p[3] = f2bf(v.w);
    *(ushort4_t*)(out + i) = p;
}

// ---------- weight transpose+convert: W(K,N) fp32 -> Wt(N,K) bf16 ----------
__global__ void transpose_f32_bf16(const float* __restrict__ W, u16t* __restrict__ Wt,
                                   int Ncols, int Krows)
{
    __shared__ u16t tile[32][33];
    int tx = threadIdx.x, ty = threadIdx.y;
    int n = blockIdx.x * 32 + tx, k = blockIdx.y * 32 + ty;
    tile[ty][tx] = f2bf(W[(size_t)k * Ncols + n]);
    __syncthreads();
    int nn = blockIdx.x * 32 + ty, kk = blockIdx.y * 32 + tx;
    Wt[(size_t)nn * Krows + kk] = tile[tx][ty];
}

// ============ shared GEMM main loop (128x128 tile, BK=64 via two 32-wide =====
// ============ sub-arrays; XCD-bijective block swizzle)                   =====
// Each [128][32] LDS sub-array keeps the m97 conflict-free read pattern.
// XCD swizzle: hardware XCD = linear_wgid % 8; remap so each XCD owns
// contiguous y-rows -> A-panel reuse lands in one XCD's L2.
#define GEMM_PROLOGUE_AND_KLOOP(GRIDX, NWG)                                       \
    __shared__ u16t As0[128 * 32], As1[128 * 32];                                 \
    __shared__ u16t Bs0[128 * 32], Bs1[128 * 32];                                 \
    const int tid  = threadIdx.x;                                                 \
    const int lane = tid & 63, w = tid >> 6;                                      \
    const int wr = (w >> 1) * 64, wc = (w & 1) * 64;                              \
    const int lr = lane & 15, quad = lane >> 4;                                   \
    const int orig = blockIdx.y * (GRIDX) + blockIdx.x;                           \
    const int lin  = (orig & 7) * ((NWG) / 8) + (orig >> 3);                      \
    const int bxs  = lin % (GRIDX), bys = lin / (GRIDX);                          \
    const int m0 = bys * 128, n0 = bxs * 128;                                     \
    f32x4 acc[4][4];                                                              \
    _Pragma("unroll")                                                             \
    for (int r = 0; r < 4; r++)                                                   \
        _Pragma("unroll")                                                         \
        for (int c = 0; c < 4; c++) acc[r][c] = (f32x4){0.f, 0.f, 0.f, 0.f};      \
    for (int k0 = 0; k0 < KDIM; k0 += 64) {                                       \
        __syncthreads();                                                          \
        _Pragma("unroll")                                                         \
        for (int cc = 0; cc < 2; cc++) {                                          \
            int slot = tid + cc * 256;                                            \
            int row = slot >> 2, ko = (slot & 3) * 8;                             \
            glds16(A  + (size_t)(m0 + row) * KDIM + k0 + ko,      As0 + slot * 8);\
            glds16(A  + (size_t)(m0 + row) * KDIM + k0 + 32 + ko, As1 + slot * 8);\
            glds16(Bt + (size_t)(n0 + row) * KDIM + k0 + ko,      Bs0 + slot * 8);\
            glds16(Bt + (size_t)(n0 + row) * KDIM + k0 + 32 + ko, Bs1 + slot * 8);\
        }                                                                         \
        __syncthreads();                                                          \
        bf16x8 a[4], b[4];                                                        \
        _Pragma("unroll")                                                         \
        for (int r = 0; r < 4; r++)                                               \
            a[r] = *(const bf16x8*)(As0 + (wr + r * 16 + lr) * 32 + quad * 8);    \
        _Pragma("unroll")                                                         \
        for (int c = 0; c < 4; c++)                                               \
            b[c] = *(const bf16x8*)(Bs0 + (wc + c * 16 + lr) * 32 + quad * 8);    \
        _Pragma("unroll")                                                         \
        for (int r = 0; r < 4; r++)                                               \
            _Pragma("unroll")                                                     \
            for (int c = 0; c < 4; c++)                                           \
                acc[r][c] = __builtin_amdgcn_mfma_f32_16x16x32_bf16(a[r], b[c], acc[r][c], 0, 0, 0); \
        _Pragma("unroll")                                                         \
        for (int r = 0; r < 4; r++)                                               \
            a[r] = *(const bf16x8*)(As1 + (wr + r * 16 + lr) * 32 + quad * 8);    \
        _Pragma("unroll")                                                         \
        for (int c = 0; c < 4; c++)                                               \
            b[c] = *(const bf16x8*)(Bs1 + (wc + c * 16 + lr) * 32 + quad * 8);    \
        _Pragma("unroll")                                                         \
        for (int r = 0; r < 4; r++)                                               \
            _Pragma("unroll")                                                     \
            for (int c = 0; c < 4; c++)                                           \
                acc[r][c] = __builtin_amdgcn_mfma_f32_16x16x32_bf16(a[r], b[c], acc[r][c], 0, 0, 0); \
    }

// ---------------- O-projection GEMM: fp32 store to d_out ----------------
__global__ void gemm_o(const u16t* __restrict__ A, const u16t* __restrict__ Bt,
                       const float* __restrict__ bias, float* __restrict__ out)
{
    GEMM_PROLOGUE_AND_KLOOP(16, 1024)
#pragma unroll
    for (int r = 0; r < 4; r++) {
#pragma unroll
        for (int c = 0; c < 4; c++) {
            int n = n0 + wc + c * 16 + lr;
            float bval = bias[n];
#pragma unroll
            for (int g = 0; g < 4; g++) {
                int m = m0 + wr + r * 16 + quad * 4 + g;
                out[(size_t)m * D_ + n] = acc[r][c][g] + bval;
            }
        }
    }
}

// ---------------- fused QKV GEMM over N=3072 (Bt = [Wqt;Wkt;Wvt]) ------------
__global__ void gemm_qkv(const u16t* __restrict__ A, const u16t* __restrict__ Bt,
                         const float* __restrict__ bq, const float* __restrict__ bk,
                         const float* __restrict__ bv,
                         u16t* __restrict__ q_t, u16t* __restrict__ k_t,
                         u16t* __restrict__ v_t,
                         const float* __restrict__ fc, const float* __restrict__ fs)
{
    GEMM_PROLOGUE_AND_KLOOP(24, 1536)
    const int region = (bxs < 16) ? 0 : ((bxs < 20) ? 1 : 2);
#pragma unroll
    for (int r = 0; r < 4; r++) {
#pragma unroll
        for (int c = 0; c < 4; c++) {
            int n = n0 + wc + c * 16 + lr;
            if (region == 0) {          // Q + RoPE
                float bval = bq[n];
                int hh = n >> 7, d = n & 127, i2 = d >> 1;
#pragma unroll
                for (int g = 0; g < 4; g++) {
                    int m = m0 + wr + r * 16 + quad * 4 + g;
                    int bb = m >> 11, s = m & (S_ - 1);
                    float v = acc[r][c][g] + bval;
                    float p = __shfl_xor(v, 1);
                    float cf = fc[s * 64 + i2], sf = fs[s * 64 + i2];
                    float o = (d & 1) ? (p * sf + v * cf) : (v * cf - p * sf);
                    q_t[(((size_t)bb * H_ + hh) * S_ + s) * HD_ + d] = f2bf(o);
                }
            } else if (region == 1) {   // K + RoPE
                int nk = n - 2048;
                float bval = bk[nk];
                int hh = nk >> 7, d = nk & 127, i2 = d >> 1;
#pragma unroll
                for (int g = 0; g < 4; g++) {
                    int m = m0 + wr + r * 16 + quad * 4 + g;
                    int bb = m >> 11, s = m & (S_ - 1);
                    float v = acc[r][c][g] + bval;
                    float p = __shfl_xor(v, 1);
                    float cf = fc[s * 64 + i2], sf = fs[s * 64 + i2];
                    float o = (d & 1) ? (p * sf + v * cf) : (v * cf - p * sf);
                    k_t[(((size_t)bb * KVH_ + hh) * S_ + s) * HD_ + d] = f2bf(o);
                }
            } else {                    // V transposed
                int nv = n - 2560;
                float bval = bv[nv];
                int kv = nv >> 7, d = nv & 127;
                int mb = m0 + wr + r * 16 + quad * 4;
                int bb = mb >> 11, s = mb & (S_ - 1);
                ushort4_t pk;
#pragma unroll
                for (int g = 0; g < 4; g++) pk[g] = f2bf(acc[r][c][g] + bval);
                *(ushort4_t*)(v_t + (((size_t)bb * KVH_ + kv) * HD_ + d) * S_ + s) = pk;
            }
        }
    }
}

// ---------------- flash attention, causal, GQA (bf16 in/out) ----------------
// 4 waves x 32 q-rows, 32x32x16 MFMA, swapped QK^T, in-register P (cvt_pk +
// permlane32_swap), XOR-swizzled K/V LDS, reg-staged double buffer,
// lgkm-only barrier. q-tile PAIRING for perfect causal balance —
// each block processes q-tiles (15-bx) then (bx): every block = 68 phases,
// grid (8,64)=512 blocks = exactly 2 equal blocks/CU, no dispatch tail.
// seg loop pinned to unroll 1 to keep code size bounded.
__global__ __launch_bounds__(256, 2) void
attn_kernel(const u16t* __restrict__ qt, const u16t* __restrict__ kt,
            const u16t* __restrict__ vt, u16t* __restrict__ att)
{
    __shared__ char Ks[2][8192];
    __shared__ char Vs[2][8192];
    const int tid  = threadIdx.x;
    const int lane = tid & 63, w = tid >> 6;          // w 0..3
    const int l5 = lane & 31, hi = lane >> 5;
    const int bh = blockIdx.y, b = bh >> 4, h = bh & 15, kv = h >> 2;
    const int bx = blockIdx.x;                        // 0..7

    const u16t* kb = kt + ((size_t)b * KVH_ + kv) * S_ * HD_;
    const u16t* vb = vt + ((size_t)b * KVH_ + kv) * HD_ * S_;

    f32x16 zero16;
#pragma unroll
    for (int j = 0; j < 16; j++) zero16[j] = 0.f;

    // staging decomposition (256 threads, 2 granules of 16B per tensor each)
    const int krow = tid >> 4, kcol = tid & 15;   // K: 32 rows x 16 col-chunks
    const int vd   = tid >> 2, vcol = tid & 3;    // V^T: 128 rows x 4 t-chunks
    const int kw0 = ((krow     ) * 256 + kcol * 16) ^ ((krow & 7) << 4);
    const int kw1 = ((krow + 16) * 256 + kcol * 16) ^ ((krow & 7) << 4);
    const int vw0 = ((vd      ) * 64 + vcol * 16) ^ (((vd >> 1) & 3) << 5);
    const int vw1 = ((vd + 64 ) * 64 + vcol * 16) ^ (((vd >> 1) & 3) << 5);

    ushort8_t kr[2][2], vr[2][2];

#pragma unroll 1
    for (int seg = 0; seg < 2; seg++) {
        const int q0 = (seg == 0 ? (15 - bx) : bx) * 128;   // heavy tile first
        const u16t* qb = qt + (((size_t)b * H_ + h) * S_ + q0) * HD_;

        // Q fragments (B-operand): col q = w*32+l5, k = ks*16 + hi*8 + e
        bf16x8 qa[8];
#pragma unroll
        for (int ks = 0; ks < 8; ks++)
            qa[ks] = *(const bf16x8*)(qb + (w * 32 + l5) * HD_ + ks * 16 + hi * 8);

        f32x16 o[4];
#pragma unroll
        for (int i = 0; i < 4; i++) o[i] = zero16;
        float lpart = 0.f;

        const int ntile = q0 / 32 + 4;   // even
#pragma unroll
        for (int p = 0; p < 2; p++) {
            int t0 = p * 32;
            kr[p][0] = *(const ushort8_t*)(kb + (size_t)(t0 + krow     ) * HD_ + kcol * 8);
            kr[p][1] = *(const ushort8_t*)(kb + (size_t)(t0 + krow + 16) * HD_ + kcol * 8);
            vr[p][0] = *(const ushort8_t*)(vb + (size_t)(vd     ) * S_ + t0 + vcol * 8);
            vr[p][1] = *(const ushort8_t*)(vb + (size_t)(vd + 64) * S_ + t0 + vcol * 8);
        }

        for (int it = 0; it < ntile; it += 2) {
#pragma unroll
            for (int p = 0; p < 2; p++) {
                const int t0 = (it + p) * 32;
                // stage prefetched regs -> LDS buffer p (swizzled writes)
                *(ushort8_t*)(Ks[p] + kw0) = kr[p][0];
                *(ushort8_t*)(Ks[p] + kw1) = kr[p][1];
                *(ushort8_t*)(Vs[p] + vw0) = vr[p][0];
                *(ushort8_t*)(Vs[p] + vw1) = vr[p][1];
                // prefetch tile it+p+2 (clamped; tail reloads tile 0 harmlessly)
                const int tn0 = (it + p + 2 < ntile) ? (it + p + 2) * 32 : 0;
                kr[p][0] = *(const ushort8_t*)(kb + (size_t)(tn0 + krow     ) * HD_ + kcol * 8);
                kr[p][1] = *(const ushort8_t*)(kb + (size_t)(tn0 + krow + 16) * HD_ + kcol * 8);
                vr[p][0] = *(const ushort8_t*)(vb + (size_t)(vd     ) * S_ + tn0 + vcol * 8);
                vr[p][1] = *(const ushort8_t*)(vb + (size_t)(vd + 64) * S_ + tn0 + vcol * 8);
                wg_barrier_lgkm();   // LDS visible; global prefetch stays in flight

                if (t0 > q0 + w * 32 + 31) continue;   // tile fully masked for this wave

                // QK^T swapped: sc[r] = S[kv = t0 + (r&3)+8*(r>>2)+4*hi][q = q0+w*32+l5]
                f32x16 sa = zero16, sb = zero16;
                __builtin_amdgcn_s_setprio(1);
#pragma unroll
                for (int ks = 0; ks < 8; ks += 2) {
                    bf16x8 kf0 = *(const bf16x8*)(Ks[p] +
                        ((l5 * 256 + ks * 32 + hi * 16) ^ ((l5 & 7) << 4)));
                    sa = __builtin_amdgcn_mfma_f32_32x32x16_bf16(kf0, qa[ks], sa, 0, 0, 0);
                    bf16x8 kf1 = *(const bf16x8*)(Ks[p] +
                        ((l5 * 256 + (ks + 1) * 32 + hi * 16) ^ ((l5 & 7) << 4)));
                    sb = __builtin_amdgcn_mfma_f32_32x32x16_bf16(kf1, qa[ks + 1], sb, 0, 0, 0);
                }
                __builtin_amdgcn_s_setprio(0);
                f32x16 sc = sa + sb;

                float pr[16];
                if (t0 + 31 <= q0 + w * 32) {            // fully unmasked for this wave
#pragma unroll
                    for (int r = 0; r < 16; r++) pr[r] = __expf(sc[r] * SCALE_);
                } else {
                    const int srow = q0 + w * 32 + l5;
#pragma unroll
                    for (int r = 0; r < 16; r++) {
                        int tc = t0 + (r & 3) + 8 * (r >> 2) + 4 * hi;
                        pr[r] = __expf(sc[r] * SCALE_ + ((tc > srow) ? -1e9f : 0.f));
                    }
                }
#pragma unroll
                for (int r = 0; r < 16; r++) lpart += pr[r];

                // pack P -> PV A-fragments entirely in-register
                unsigned d0[4], d1[4];
#pragma unroll
                for (int q4 = 0; q4 < 4; q4++) {
                    d0[q4] = cvt_pk_bf16(pr[4 * q4 + 0], pr[4 * q4 + 1]);
                    d1[q4] = cvt_pk_bf16(pr[4 * q4 + 2], pr[4 * q4 + 3]);
                }
                permlane32_swap(d0[0], d0[1]);
                permlane32_swap(d1[0], d1[1]);
                permlane32_swap(d0[2], d0[3]);
                permlane32_swap(d1[2], d1[3]);
                union { unsigned u[4]; bf16x8 v; } pa0, pa1;
                pa0.u[0] = d0[0]; pa0.u[1] = d1[0]; pa0.u[2] = d0[1]; pa0.u[3] = d1[1];
                pa1.u[0] = d0[2]; pa1.u[1] = d1[2]; pa1.u[2] = d0[3]; pa1.u[3] = d1[3];

                __builtin_amdgcn_s_setprio(1);
#pragma unroll
                for (int dt = 0; dt < 4; dt++) {
                    bf16x8 vf0 = *(const bf16x8*)(Vs[p] +
                        (((dt * 32 + l5) * 64 + hi * 16) ^ (((l5 >> 1) & 3) << 5)));
                    o[dt] = __builtin_amdgcn_mfma_f32_32x32x16_bf16(pa0.v, vf0, o[dt], 0, 0, 0);
                    bf16x8 vf1 = *(const bf16x8*)(Vs[p] +
                        (((dt * 32 + l5) * 64 + 32 + hi * 16) ^ (((l5 >> 1) & 3) << 5)));
                    o[dt] = __builtin_amdgcn_mfma_f32_32x32x16_bf16(pa1.v, vf1, o[dt], 0, 0, 0);
                }
                __builtin_amdgcn_s_setprio(0);
            }
        }

        // epilogue: finish row sums (halves hold disjoint kv subsets), normalize, store
        float lf = lpart + __shfl_xor(lpart, 32);
        float linv = 1.f / lf;                       // valid for q-row = l5 (both halves)
#pragma unroll
        for (int r = 0; r < 16; r++) {
            int qrow = (r & 3) + 8 * (r >> 2) + 4 * hi;
            float iv = __shfl(linv, qrow);
            int s = q0 + w * 32 + qrow;
            u16t* orow = att + ((size_t)(b * S_ + s)) * D_ + h * HD_ + l5;
#pragma unroll
            for (int dt = 0; dt < 4; dt++)
                orow[dt * 32] = f2bf(o[dt][r] * iv);
        }
    }
}

extern "C" void kernel_launch(void* const* d_in, const int* in_sizes, int n_in,
                              void* d_out, int out_size, void* d_ws, size_t ws_size,
                              hipStream_t stream)
{
    const float* x  = (const float*)d_in[0];
    const float* Wq = (const float*)d_in[1];
    const float* bq = (const float*)d_in[2];
    const float* Wk = (const float*)d_in[3];
    const float* bk = (const float*)d_in[4];
    const float* Wv = (const float*)d_in[5];
    const float* bv = (const float*)d_in[6];
    const float* Wo = (const float*)d_in[7];
    const float* bo = (const float*)d_in[8];
    const float* fc = (const float*)d_in[9];
    const float* fs = (const float*)d_in[10];
    // d_in[11] (mask): fixed causal mask, analytic. d_in[12] (start_pos): 0.

    const size_t M1 = (size_t)1024 * 1024;
    u16t* ws   = (u16t*)d_ws;
    u16t* x_bf = ws;
    u16t* att  = ws;
    u16t* Wqt  = ws + 16 * M1;
    u16t* Wot  = ws + 16 * M1;
    u16t* Wkt  = ws + 20 * M1;
    u16t* Wvt  = ws + 21 * M1;
    u16t* k_t  = ws + 22 * M1;
    u16t* v_t  = ws + 26 * M1;
    u16t* q_t  = (u16t*)d_out;

    f32_to_bf16<<<dim3(16384), 256, 0, stream>>>(x, x_bf);

    dim3 tb(32, 32);
    transpose_f32_bf16<<<dim3(64, 64), tb, 0, stream>>>(Wq, Wqt, 2048, 2048);
    transpose_f32_bf16<<<dim3(16, 64), tb, 0, stream>>>(Wk, Wkt, 512, 2048);
    transpose_f32_bf16<<<dim3(16, 64), tb, 0, stream>>>(Wv, Wvt, 512, 2048);

    gemm_qkv<<<dim3(24, 64), 256, 0, stream>>>(x_bf, Wqt, bq, bk, bv,
                                               q_t, k_t, v_t, fc, fs);

    attn_kernel<<<dim3(8, 64), 256, 0, stream>>>(q_t, k_t, v_t, att);

    transpose_f32_bf16<<<dim3(64, 64), tb, 0, stream>>>(Wo, Wot, 2048, 2048);

    gemm_o<<<dim3(16, 64), 256, 0, stream>>>(att, Wot, bo, (float*)d_out);
}